// Round 6
// baseline (1384.998 us; speedup 1.0000x reference)
//
#include <hip/hip_runtime.h>
#include <hip/hip_bf16.h>

#define TLEN 4096
#define HPADT 512
#define SQRT_HALF 0.70710678118654752f

typedef __attribute__((ext_vector_type(8))) short short8;
typedef __attribute__((ext_vector_type(4))) float floatx4;
typedef __attribute__((ext_vector_type(4))) unsigned short ushort4v;

#define MFMA_BF16(a, b, c) __builtin_amdgcn_mfma_f32_16x16x32_bf16((a), (b), (c), 0, 0, 0)

__device__ __forceinline__ float bf2f(unsigned short u) {
  union { unsigned int i; float f; } v; v.i = ((unsigned int)u) << 16; return v.f;
}
__device__ __forceinline__ unsigned short f2bf(float x) {
  union { float f; unsigned int i; } v; v.f = x;
  unsigned int r = v.i + 0x7FFFu + ((v.i >> 16) & 1u);
  return (unsigned short)(r >> 16);
}
__device__ __forceinline__ short8 ld8(const unsigned short* p) { return *(const short8*)p; }

// ---- 128-elem-row staging (final1, 256-thread blocks) ----
template <int NI>
__device__ __forceinline__ void stage128(unsigned short* lds, const unsigned short* src,
                                         int stride, int tid) {
  #pragma unroll
  for (int inst = 0; inst < NI; ++inst) {
    int qb = inst * 256 + (tid & 192);
    int q = qb + (tid & 63);
    int r = q >> 4;
    int c = (q & 15) ^ (r & 15);
    __builtin_amdgcn_global_load_lds(
        (const __attribute__((address_space(1))) unsigned int*)(src + (size_t)r * stride + (c << 3)),
        (__attribute__((address_space(3))) unsigned int*)(lds + qb * 8),
        16, 0, 0);
  }
}
__device__ __forceinline__ short8 frag128(const unsigned short* lds, int r, int cj) {
  return *(const short8*)(lds + r * 128 + ((cj ^ (r & 15)) << 3));
}

// ---- 64-elem-row staging, 512-thread blocks (loop GEMMs, BK=64) ----
// unit = 64 rows of 64 bf16 (8 KB), XOR-swizzled: chunk c of row r at slot c^(r&7).
template <int NI>
__device__ __forceinline__ void stage64w8(unsigned short* lds, const unsigned short* src,
                                          int stride, int tid) {
  #pragma unroll
  for (int inst = 0; inst < NI; ++inst) {
    int qb = inst * 512 + (tid & 448);   // wave-uniform
    int q = qb + (tid & 63);
    int r = q >> 3;
    int c = (q & 7) ^ (r & 7);
    __builtin_amdgcn_global_load_lds(
        (const __attribute__((address_space(1))) unsigned int*)(src + (size_t)r * stride + (c << 3)),
        (__attribute__((address_space(3))) unsigned int*)(lds + qb * 8),
        16, 0, 0);
  }
}
// one unit = 64 rows: rows 0-31 from f (F-panel), rows 32-63 from g (G-panel)
__device__ __forceinline__ void stageA(unsigned short* lds, const unsigned short* f,
                                       const unsigned short* g, int strideA, int tid) {
  int qb = (tid & 448);
  int q = qb + (tid & 63);
  int r = q >> 3;
  int c = (q & 7) ^ (r & 7);
  const unsigned short* src =
      (r < 32 ? f + (size_t)r * strideA : g + (size_t)(r - 32) * strideA) + (c << 3);
  __builtin_amdgcn_global_load_lds(
      (const __attribute__((address_space(1))) unsigned int*)src,
      (__attribute__((address_space(3))) unsigned int*)(lds + qb * 8),
      16, 0, 0);
}
__device__ __forceinline__ short8 frag64(const unsigned short* lds, int r, int cj) {
  return *(const short8*)(lds + r * 64 + ((cj ^ (r & 7)) << 3));
}

// Counted waits (per-wave outstanding stage instructions of the NEXT step)
__device__ __forceinline__ void wait_vm7() { asm volatile("s_waitcnt vmcnt(7)" ::: "memory"); }
__device__ __forceinline__ void wait_vm5() { asm volatile("s_waitcnt vmcnt(5)" ::: "memory"); }
__device__ __forceinline__ void wait_vm0() { asm volatile("s_waitcnt vmcnt(0)" ::: "memory"); }

// ============ weight pre-cast, split into small grid-strided dispatches ============
__global__ __launch_bounds__(256) void cast_wa_kernel(
    const float* __restrict__ fw, const float* __restrict__ gw,
    unsigned short* __restrict__ WA, int base, int count)
{
  for (int i = blockIdx.x * 256 + threadIdx.x; i < count; i += gridDim.x * 256) {
    size_t idx = (size_t)base + i;
    size_t l = idx >> 16;
    int o = (int)((idx >> 7) & 511);
    int i4 = (int)(idx & 127) * 4;
    const float4* fp = (const float4*)(fw + (((l * 512 + o) * 512 + i4) * 2));
    const float4* gp = (const float4*)(gw + (((l * 512 + o) * 512 + i4) * 2));
    float4 f0 = fp[0], f1v = fp[1];
    float4 g0 = gp[0], g1 = gp[1];
    size_t base0 = ((l * 2 + 0) * 1024);
    size_t base1 = ((l * 2 + 1) * 1024);
    *(ushort4v*)&WA[(base0 + o) * 512 + i4]       = (ushort4v){f2bf(f0.x), f2bf(f0.z), f2bf(f1v.x), f2bf(f1v.z)};
    *(ushort4v*)&WA[(base1 + o) * 512 + i4]       = (ushort4v){f2bf(f0.y), f2bf(f0.w), f2bf(f1v.y), f2bf(f1v.w)};
    *(ushort4v*)&WA[(base0 + 512 + o) * 512 + i4] = (ushort4v){f2bf(g0.x), f2bf(g0.z), f2bf(g1.x), f2bf(g1.z)};
    *(ushort4v*)&WA[(base1 + 512 + o) * 512 + i4] = (ushort4v){f2bf(g0.y), f2bf(g0.w), f2bf(g1.y), f2bf(g1.w)};
  }
}

__global__ __launch_bounds__(256) void cast_rs_kernel(
    const float* __restrict__ rw, const float* __restrict__ sw,
    unsigned short* __restrict__ RS, int base, int count)
{
  for (int i = blockIdx.x * 256 + threadIdx.x; i < count; i += gridDim.x * 256) {
    size_t idx = (size_t)base + i;
    size_t l = idx >> 16;
    int o = (int)((idx >> 7) & 511);
    int i4 = (int)(idx & 127) * 4;
    float4 r4 = *(const float4*)(rw + ((l * 512 + o) * 512 + i4));
    float4 s4 = *(const float4*)(sw + ((l * 512 + o) * 512 + i4));
    *(ushort4v*)&RS[(l * 1024 + o) * 512 + i4]       = (ushort4v){f2bf(r4.x), f2bf(r4.y), f2bf(r4.z), f2bf(r4.w)};
    *(ushort4v*)&RS[(l * 1024 + 512 + o) * 512 + i4] = (ushort4v){f2bf(s4.x), f2bf(s4.y), f2bf(s4.z), f2bf(s4.w)};
  }
}

__global__ __launch_bounds__(256) void cast_misc_kernel(
    const float* __restrict__ cf, const float* __restrict__ cg,
    const float* __restrict__ f1, const float* __restrict__ fb,
    const float* __restrict__ cfb, const float* __restrict__ gb,
    const float* __restrict__ cgb,
    unsigned short* __restrict__ CA, unsigned short* __restrict__ F1c,
    float* __restrict__ fgb)
{
  const int total = 491520 + 65536 + 30720;
  for (int i = blockIdx.x * 256 + threadIdx.x; i < total; i += gridDim.x * 256) {
    if (i < 491520) {
      size_t idx = i;
      size_t l = idx >> 14;
      int o = (int)((idx >> 5) & 511);
      int i4 = (int)(idx & 31) * 4;
      float4 f4 = *(const float4*)(cf + ((l * 512 + o) * 128 + i4));
      float4 g4 = *(const float4*)(cg + ((l * 512 + o) * 128 + i4));
      *(ushort4v*)&CA[(l * 1024 + o) * 128 + i4]       = (ushort4v){f2bf(f4.x), f2bf(f4.y), f2bf(f4.z), f2bf(f4.w)};
      *(ushort4v*)&CA[(l * 1024 + 512 + o) * 128 + i4] = (ushort4v){f2bf(g4.x), f2bf(g4.y), f2bf(g4.z), f2bf(g4.w)};
    } else if (i < 491520 + 65536) {
      size_t idx = i - 491520;
      float4 v = *(const float4*)(f1 + idx * 4);
      *(ushort4v*)&F1c[idx * 4] = (ushort4v){f2bf(v.x), f2bf(v.y), f2bf(v.z), f2bf(v.w)};
    } else {
      int idx = i - (491520 + 65536);
      int l = idx >> 10, r = idx & 1023;
      float v;
      if (r < 512) v = fb[l * 512 + r] + cfb[l * 512 + r];
      else         v = gb[l * 512 + r - 512] + cgb[l * 512 + r - 512];
      fgb[idx] = v;
    }
  }
}

// ============ upsample ============

__global__ __launch_bounds__(256) void upsample1_kernel(
    const float* __restrict__ c, const float* __restrict__ up_w,
    const float* __restrict__ up_b, float* __restrict__ u1)
{
  int x = threadIdx.x;
  int h = blockIdx.x;
  const float* w = up_w;
  float acc = 0.f;
  int k1 = (23 - x) & 15;
  #pragma unroll
  for (int dk = 0; dk < 2; ++dk) {
    int kx = k1 + 16 * dk;
    int num = x + kx - 23;
    if (num >= 0) {
      int qq = num >> 4;
      if (qq < 16) {
        #pragma unroll
        for (int ky = 0; ky < 3; ++ky) {
          int hh = h + ky - 1;
          if (hh >= 0 && hh < 128)
            acc += c[hh * 16 + qq] * w[(2 - ky) * 32 + (31 - kx)];
        }
      }
    }
  }
  acc += up_b[0];
  u1[h * 256 + x] = acc > 0.f ? acc : 0.4f * acc;
}

__global__ __launch_bounds__(256) void upsample2_kernel(
    const float* __restrict__ u1, const float* __restrict__ up_w,
    const float* __restrict__ up_b, unsigned short* __restrict__ cu)
{
  int x = blockIdx.x * 256 + threadIdx.x;
  int h = blockIdx.y;
  const float* w = up_w + 96;
  float acc = 0.f;
  int k1 = (23 - x) & 15;
  #pragma unroll
  for (int dk = 0; dk < 2; ++dk) {
    int kx = k1 + 16 * dk;
    int num = x + kx - 23;
    if (num >= 0) {
      int qq = num >> 4;
      if (qq < 256) {
        #pragma unroll
        for (int ky = 0; ky < 3; ++ky) {
          int hh = h + ky - 1;
          if (hh >= 0 && hh < 128)
            acc += u1[hh * 256 + qq] * w[(2 - ky) * 32 + (31 - kx)];
        }
      }
    }
  }
  acc += up_b[1];
  acc = acc > 0.f ? acc : 0.4f * acc;
  cu[(size_t)x * 128 + h] = f2bf(acc);
}

// ============ front conv -> h[t][512] ============
__global__ __launch_bounds__(256) void front_kernel(
    const float* __restrict__ x, const float* __restrict__ fw, const float* __restrict__ fb,
    float* __restrict__ hf, unsigned short* __restrict__ hbf)
{
  __shared__ float xs[40];
  int tid = threadIdx.x;
  int o = blockIdx.y * 256 + tid;
  int t0 = blockIdx.x * 8;
  if (tid < 39) {
    int gx = t0 - 31 + tid;
    xs[tid] = (gx >= 0) ? x[gx] : 0.f;
  }
  __syncthreads();
  float w[32];
  #pragma unroll
  for (int k = 0; k < 32; ++k) w[k] = fw[o * 32 + k];
  float b = fb[o];
  #pragma unroll
  for (int j = 0; j < 8; ++j) {
    float acc = b;
    #pragma unroll
    for (int k = 0; k < 32; ++k) acc += w[k] * xs[j + k];
    acc = acc > 0.f ? acc : 0.f;
    int t = t0 + j;
    hf[(size_t)t * 512 + o] = acc;
    hbf[(size_t)(HPADT + t) * 512 + o] = f2bf(acc);
  }
}

// ============ gemm_a_smalld: d <= 64, 32oc x 256t, 512 thr, 1 blk/CU ============
// Union X staging (320 rows covers 256+d), BK=64, depth-2 counted-vmcnt pipeline.
// LDS: U 2x320x64 (80 KB) + Aw 2x128x64 (32 KB) = 112 KB.
// Per conv step: 7 stage instrs/wave (5 U + 2 A); cond: 5 (4 U + 1 A).
__global__ __launch_bounds__(512, 2) void gemm_a_smalld_kernel(
    const unsigned short* __restrict__ WA,   // [2][1024][512]
    const unsigned short* __restrict__ CA,   // [1024][128]
    const float* __restrict__ fgb,           // [1024]
    const unsigned short* __restrict__ hbf,  // [(HPADT+T+slack)][512]
    const unsigned short* __restrict__ cu,   // [T][128]
    unsigned short* __restrict__ obf,        // [T][512]
    const int d)
{
  __shared__ unsigned short U[2][320 * 64];
  __shared__ unsigned short Aw[2][128 * 64];   // rows: 0-31 F0, 32-63 G0, 64-95 F1, 96-127 G1

  const int tid = threadIdx.x;
  const int lane = tid & 63;
  const int wave = tid >> 6;                 // 0..7
  const int lm = lane & 15, qd = lane >> 4;
  const int n0 = blockIdx.x * 256;
  const int m0 = blockIdx.y * 32;
  const int wn = wave * 32;
  const int NS = 10;

  floatx4 accF[2][2], accG[2][2];
  #pragma unroll
  for (int a = 0; a < 2; ++a)
    #pragma unroll
    for (int b = 0; b < 2; ++b) {
      accF[a][b] = (floatx4){0.f, 0.f, 0.f, 0.f};
      accG[a][b] = (floatx4){0.f, 0.f, 0.f, 0.f};
    }

  auto stage_step = [&](int s, int b) {
    if (s < 8) {
      int k0 = s * 64;
      stage64w8<5>(&U[b][0], hbf + (size_t)(HPADT + n0 - d) * 512 + k0, 512, tid);
      stageA(&Aw[b][0],       WA + (size_t)m0 * 512 + k0,
                              WA + (size_t)(512 + m0) * 512 + k0, 512, tid);
      stageA(&Aw[b][64 * 64], WA + 524288 + (size_t)m0 * 512 + k0,
                              WA + 524288 + (size_t)(512 + m0) * 512 + k0, 512, tid);
    } else {
      int k0 = (s - 8) * 64;
      stage64w8<4>(&U[b][0], cu + (size_t)n0 * 128 + k0, 128, tid);
      stageA(&Aw[b][0], CA + (size_t)m0 * 128 + k0,
                        CA + (size_t)(512 + m0) * 128 + k0, 128, tid);
    }
  };

  stage_step(0, 0);
  #pragma unroll 1
  for (int s = 0; s < NS; ++s) {
    if (s + 1 < NS) stage_step(s + 1, (s + 1) & 1);
    if (s + 1 < 8)        wait_vm7();   // outstanding = conv stage(s+1)
    else if (s + 1 < NS)  wait_vm5();   // outstanding = cond stage(s+1)
    else                  wait_vm0();
    __builtin_amdgcn_s_barrier();
    __builtin_amdgcn_sched_barrier(0);
    const unsigned short* u  = &U[s & 1][0];
    const unsigned short* aw = &Aw[s & 1][0];
    __builtin_amdgcn_s_setprio(1);
    if (s < 8) {
      #pragma unroll
      for (int j = 0; j < 2; ++j) {
        int cj = j * 4 + qd;
        short8 f0[2], g0[2], f1[2], g1[2], xv[2], yv[2];
        #pragma unroll
        for (int mt = 0; mt < 2; ++mt) {
          f0[mt] = frag64(aw, mt * 16 + lm, cj);
          g0[mt] = frag64(aw, 32 + mt * 16 + lm, cj);
          f1[mt] = frag64(aw, 64 + mt * 16 + lm, cj);
          g1[mt] = frag64(aw, 96 + mt * 16 + lm, cj);
        }
        #pragma unroll
        for (int nt = 0; nt < 2; ++nt) {
          xv[nt] = frag64(u, wn + nt * 16 + lm, cj);        // t - d (tap0)
          yv[nt] = frag64(u, d + wn + nt * 16 + lm, cj);    // t     (tap1)
        }
        #pragma unroll
        for (int mt = 0; mt < 2; ++mt)
          #pragma unroll
          for (int nt = 0; nt < 2; ++nt) {
            accF[mt][nt] = MFMA_BF16(f0[mt], xv[nt], accF[mt][nt]);
            accF[mt][nt] = MFMA_BF16(f1[mt], yv[nt], accF[mt][nt]);
            accG[mt][nt] = MFMA_BF16(g0[mt], xv[nt], accG[mt][nt]);
            accG[mt][nt] = MFMA_BF16(g1[mt], yv[nt], accG[mt][nt]);
          }
      }
    } else {
      #pragma unroll
      for (int j = 0; j < 2; ++j) {
        int cj = j * 4 + qd;
        short8 fv[2], gv[2], xv[2];
        #pragma unroll
        for (int mt = 0; mt < 2; ++mt) {
          fv[mt] = frag64(aw, mt * 16 + lm, cj);
          gv[mt] = frag64(aw, 32 + mt * 16 + lm, cj);
        }
        #pragma unroll
        for (int nt = 0; nt < 2; ++nt) xv[nt] = frag64(u, wn + nt * 16 + lm, cj);
        #pragma unroll
        for (int mt = 0; mt < 2; ++mt)
          #pragma unroll
          for (int nt = 0; nt < 2; ++nt) {
            accF[mt][nt] = MFMA_BF16(fv[mt], xv[nt], accF[mt][nt]);
            accG[mt][nt] = MFMA_BF16(gv[mt], xv[nt], accG[mt][nt]);
          }
      }
    }
    __builtin_amdgcn_s_setprio(0);
    __builtin_amdgcn_sched_barrier(0);
    __builtin_amdgcn_s_barrier();   // all waves done reading buf before it is restaged
    __builtin_amdgcn_sched_barrier(0);
  }

  #pragma unroll
  for (int mt = 0; mt < 2; ++mt) {
    int oc0 = m0 + mt * 16 + qd * 4;
    floatx4 fb4 = *(const floatx4*)&fgb[oc0];
    floatx4 gb4 = *(const floatx4*)&fgb[512 + oc0];
    #pragma unroll
    for (int nt = 0; nt < 2; ++nt) {
      int t = n0 + wn + nt * 16 + lm;
      ushort4v o4;
      #pragma unroll
      for (int r = 0; r < 4; ++r) {
        float f = accF[mt][nt][r] + fb4[r];
        float g = accG[mt][nt][r] + gb4[r];
        float ef = __expf(-2.f * f);
        float th = (1.f - ef) / (1.f + ef);
        float sg = 1.f / (1.f + __expf(-g));
        o4[r] = f2bf(th * sg);
      }
      *(ushort4v*)&obf[(size_t)t * 512 + oc0] = o4;
    }
  }
}

// ============ gemm_a_bigd: d >= 128, tap-sequential, 32oc x 256t, 512 thr ============
// LDS: U 2x256x64 (64 KB) + Aw 2x64x64 (16 KB) = 80 KB. 5 stage instrs/wave/step.
__global__ __launch_bounds__(512, 2) void gemm_a_bigd_kernel(
    const unsigned short* __restrict__ WA,
    const unsigned short* __restrict__ CA,
    const float* __restrict__ fgb,
    const unsigned short* __restrict__ hbf,
    const unsigned short* __restrict__ cu,
    unsigned short* __restrict__ obf,
    const int d)
{
  __shared__ unsigned short U[2][256 * 64];
  __shared__ unsigned short Aw[2][64 * 64];   // rows 0-31 F(tap), 32-63 G(tap)

  const int tid = threadIdx.x;
  const int lane = tid & 63;
  const int wave = tid >> 6;
  const int lm = lane & 15, qd = lane >> 4;
  const int n0 = blockIdx.x * 256;
  const int m0 = blockIdx.y * 32;
  const int wn = wave * 32;
  const int NS = 18;

  floatx4 accF[2][2], accG[2][2];
  #pragma unroll
  for (int a = 0; a < 2; ++a)
    #pragma unroll
    for (int b = 0; b < 2; ++b) {
      accF[a][b] = (floatx4){0.f, 0.f, 0.f, 0.f};
      accG[a][b] = (floatx4){0.f, 0.f, 0.f, 0.f};
    }

  auto stage_step = [&](int s, int b) {
    if (s < 16) {
      int tap = s >> 3;
      int k0 = (s & 7) * 64;
      stage64w8<4>(&U[b][0], hbf + (size_t)(HPADT + n0 - (tap ? 0 : d)) * 512 + k0, 512, tid);
      stageA(&Aw[b][0], WA + (size_t)tap * 524288 + (size_t)m0 * 512 + k0,
                        WA + (size_t)tap * 524288 + (size_t)(512 + m0) * 512 + k0, 512, tid);
    } else {
      int k0 = (s - 16) * 64;
      stage64w8<4>(&U[b][0], cu + (size_t)n0 * 128 + k0, 128, tid);
      stageA(&Aw[b][0], CA + (size_t)m0 * 128 + k0,
                        CA + (size_t)(512 + m0) * 128 + k0, 128, tid);
    }
  };

  stage_step(0, 0);
  #pragma unroll 1
  for (int s = 0; s < NS; ++s) {
    if (s + 1 < NS) stage_step(s + 1, (s + 1) & 1);
    if (s + 1 < NS) wait_vm5();
    else            wait_vm0();
    __builtin_amdgcn_s_barrier();
    __builtin_amdgcn_sched_barrier(0);
    const unsigned short* u  = &U[s & 1][0];
    const unsigned short* aw = &Aw[s & 1][0];
    __builtin_amdgcn_s_setprio(1);
    #pragma unroll
    for (int j = 0; j < 2; ++j) {
      int cj = j * 4 + qd;
      short8 fv[2], gv[2], xv[2];
      #pragma unroll
      for (int mt = 0; mt < 2; ++mt) {
        fv[mt] = frag64(aw, mt * 16 + lm, cj);
        gv[mt] = frag64(aw, 32 + mt * 16 + lm, cj);
      }
      #pragma unroll
      for (int nt = 0; nt < 2; ++nt) xv[nt] = frag64(u, wn + nt * 16 + lm, cj);
      #pragma unroll
      for (int mt = 0; mt < 2; ++mt)
        #pragma unroll
        for (int nt = 0; nt < 2; ++nt) {
          accF[mt][nt] = MFMA_BF16(fv[mt], xv[nt], accF[mt][nt]);
          accG[mt][nt] = MFMA_BF16(gv[mt], xv[nt], accG[mt][nt]);
        }
    }
    __builtin_amdgcn_s_setprio(0);
    __builtin_amdgcn_sched_barrier(0);
    __builtin_amdgcn_s_barrier();
    __builtin_amdgcn_sched_barrier(0);
  }

  #pragma unroll
  for (int mt = 0; mt < 2; ++mt) {
    int oc0 = m0 + mt * 16 + qd * 4;
    floatx4 fb4 = *(const floatx4*)&fgb[oc0];
    floatx4 gb4 = *(const floatx4*)&fgb[512 + oc0];
    #pragma unroll
    for (int nt = 0; nt < 2; ++nt) {
      int t = n0 + wn + nt * 16 + lm;
      ushort4v o4;
      #pragma unroll
      for (int r = 0; r < 4; ++r) {
        float f = accF[mt][nt][r] + fb4[r];
        float g = accG[mt][nt][r] + gb4[r];
        float ef = __expf(-2.f * f);
        float th = (1.f - ef) / (1.f + ef);
        float sg = 1.f / (1.f + __expf(-g));
        o4[r] = f2bf(th * sg);
      }
      *(ushort4v*)&obf[(size_t)t * 512 + oc0] = o4;
    }
  }
}

// ============ gemm_b: dual R/S, 32oc x 256t, 512 thr, 1 blk/CU ============
// LDS: U 2x256x64 + Aw 2x64x64 = 80 KB. 5 stage instrs/wave/step. NS=8.
__global__ __launch_bounds__(512, 2) void gemm_b_kernel(
    const unsigned short* __restrict__ RS,   // [1024][512]
    const float* __restrict__ rb, const float* __restrict__ sb,
    const unsigned short* __restrict__ obf,  // [T][512]
    float* __restrict__ hf, unsigned short* __restrict__ hbf,
    float* __restrict__ skip, unsigned short* __restrict__ skipbf,
    const int first, const int last)
{
  __shared__ unsigned short U[2][256 * 64];
  __shared__ unsigned short Aw[2][64 * 64];   // rows 0-31 R, 32-63 S

  const int tid = threadIdx.x;
  const int lane = tid & 63;
  const int wave = tid >> 6;
  const int lm = lane & 15, qd = lane >> 4;
  const int n0 = blockIdx.x * 256;
  const int m0 = blockIdx.y * 32;
  const int wn = wave * 32;
  const int NS = 8;

  floatx4 accR[2][2], accS[2][2];
  #pragma unroll
  for (int a = 0; a < 2; ++a)
    #pragma unroll
    for (int b = 0; b < 2; ++b) {
      accR[a][b] = (floatx4){0.f, 0.f, 0.f, 0.f};
      accS[a][b] = (floatx4){0.f, 0.f, 0.f, 0.f};
    }

  auto stage_step = [&](int s, int b) {
    int k0 = s * 64;
    stage64w8<4>(&U[b][0], obf + (size_t)n0 * 512 + k0, 512, tid);
    stageA(&Aw[b][0], RS + (size_t)m0 * 512 + k0,
                      RS + (size_t)(512 + m0) * 512 + k0, 512, tid);
  };

  stage_step(0, 0);
  #pragma unroll 1
  for (int s = 0; s < NS; ++s) {
    if (s + 1 < NS) stage_step(s + 1, (s + 1) & 1);
    if (s + 1 < NS) wait_vm5();
    else            wait_vm0();
    __builtin_amdgcn_s_barrier();
    __builtin_amdgcn_sched_barrier(0);
    const unsigned short* u  = &U[s & 1][0];
    const unsigned short* aw = &Aw[s & 1][0];
    __builtin_amdgcn_s_setprio(1);
    #pragma unroll
    for (int j = 0; j < 2; ++j) {
      int cj = j * 4 + qd;
      short8 rv[2], sv[2], xv[2];
      #pragma unroll
      for (int mt = 0; mt < 2; ++mt) {
        rv[mt] = frag64(aw, mt * 16 + lm, cj);
        sv[mt] = frag64(aw, 32 + mt * 16 + lm, cj);
      }
      #pragma unroll
      for (int nt = 0; nt < 2; ++nt) xv[nt] = frag64(u, wn + nt * 16 + lm, cj);
      #pragma unroll
      for (int mt = 0; mt < 2; ++mt)
        #pragma unroll
        for (int nt = 0; nt < 2; ++nt) {
          accR[mt][nt] = MFMA_BF16(rv[mt], xv[nt], accR[mt][nt]);
          accS[mt][nt] = MFMA_BF16(sv[mt], xv[nt], accS[mt][nt]);
        }
    }
    __builtin_amdgcn_s_setprio(0);
    __builtin_amdgcn_sched_barrier(0);
    __builtin_amdgcn_s_barrier();
    __builtin_amdgcn_sched_barrier(0);
  }

  #pragma unroll
  for (int mt = 0; mt < 2; ++mt) {
    int oc0 = m0 + mt * 16 + qd * 4;
    floatx4 rb4 = *(const floatx4*)&rb[oc0];
    floatx4 sb4 = *(const floatx4*)&sb[oc0];
    #pragma unroll
    for (int nt = 0; nt < 2; ++nt) {
      int t = n0 + wn + nt * 16 + lm;
      size_t base = (size_t)t * 512 + oc0;
      floatx4 h4 = *(const floatx4*)&hf[base];
      floatx4 s4;
      if (first) s4 = (floatx4){0.f, 0.f, 0.f, 0.f};
      else s4 = *(const floatx4*)&skip[base];
      ushort4v hb4;
      #pragma unroll
      for (int r = 0; r < 4; ++r) {
        float hv = (h4[r] + accR[mt][nt][r] + rb4[r]) * SQRT_HALF;
        h4[r] = hv;
        hb4[r] = f2bf(hv);
        s4[r] = s4[r] + accS[mt][nt][r] + sb4[r];
      }
      *(floatx4*)&hf[base] = h4;
      *(ushort4v*)&hbf[(size_t)(HPADT + t) * 512 + oc0] = hb4;
      *(floatx4*)&skip[base] = s4;
      if (last) {
        ushort4v sk4;
        #pragma unroll
        for (int r = 0; r < 4; ++r) sk4[r] = f2bf(s4[r] > 0.f ? s4[r] : 0.f);
        *(ushort4v*)&skipbf[base] = sk4;
      }
    }
  }
}

// ============ final1: tile 64 x 128, BK=128, dbuf LDS (96 KB) ============
__global__ __launch_bounds__(256) void final1_kernel(
    const unsigned short* __restrict__ W1,
    const float* __restrict__ b1,
    const unsigned short* __restrict__ skipbf,
    unsigned short* __restrict__ t1)
{
  __shared__ unsigned short Aw[2][64 * 128];
  __shared__ unsigned short Xs[2][128 * 128];

  const int tid = threadIdx.x;
  const int lane = tid & 63;
  const int wave = tid >> 6;
  const int lm = lane & 15, qd = lane >> 4;
  const int n0 = blockIdx.x * 128;
  const int m0 = blockIdx.y * 64;
  const int wm = (wave & 1) * 32;
  const int wn = (wave >> 1) * 64;

  floatx4 acc[2][4];
  #pragma unroll
  for (int a = 0; a < 2; ++a)
    #pragma unroll
    for (int b = 0; b < 4; ++b) acc[a][b] = (floatx4){0.f, 0.f, 0.f, 0.f};

  auto stage_step = [&](int s, int b) {
    int k0 = s * 128;
    stage128<4>(&Aw[b][0], W1 + (size_t)m0 * 512 + k0, 512, tid);
    stage128<8>(&Xs[b][0], skipbf + (size_t)n0 * 512 + k0, 512, tid);
  };

  stage_step(0, 0);
  for (int s = 0; s < 4; ++s) {
    __syncthreads();
    if (s < 3) stage_step(s + 1, (s + 1) & 1);
    const unsigned short* aw = &Aw[s & 1][0];
    const unsigned short* xs = &Xs[s & 1][0];
    #pragma unroll
    for (int j = 0; j < 4; ++j) {
      int cj = j * 4 + qd;
      short8 a[2], xv[4];
      a[0] = frag128(aw, wm + lm, cj);
      a[1] = frag128(aw, wm + 16 + lm, cj);
      #pragma unroll
      for (int nt = 0; nt < 4; ++nt) xv[nt] = frag128(xs, wn + nt * 16 + lm, cj);
      #pragma unroll
      for (int mt = 0; mt < 2; ++mt)
        #pragma unroll
        for (int nt = 0; nt < 4; ++nt)
          acc[mt][nt] = MFMA_BF16(a[mt], xv[nt], acc[mt][nt]);
    }
  }

  #pragma unroll
  for (int mt = 0; mt < 2; ++mt) {
    int oc0 = m0 + wm + mt * 16 + qd * 4;
    floatx4 b4 = *(const floatx4*)&b1[oc0];
    #pragma unroll
    for (int nt = 0; nt < 4; ++nt) {
      int t = n0 + wn + nt * 16 + lm;
      ushort4v o4;
      #pragma unroll
      for (int r = 0; r < 4; ++r) {
        float v = acc[mt][nt][r] + b4[r];
        o4[r] = f2bf(v > 0.f ? v : 0.f);
      }
      *(ushort4v*)&t1[(size_t)t * 512 + oc0] = o4;
    }
  }
}

// ============ final2: one wave per t, coalesced + shuffle reduce ============
__global__ __launch_bounds__(256) void final2_kernel(
    const float* __restrict__ W2, const float* __restrict__ b2,
    const unsigned short* __restrict__ t1, float* __restrict__ out)
{
  int wave = threadIdx.x >> 6, lane = threadIdx.x & 63;
  int t = blockIdx.x * 4 + wave;
  short8 v = ld8(t1 + (size_t)t * 512 + lane * 8);
  float a0 = 0.f, a1 = 0.f;
  #pragma unroll
  for (int r = 0; r < 8; ++r) {
    float f = bf2f((unsigned short)v[r]);
    a0 += W2[lane * 8 + r] * f;
    a1 += W2[512 + lane * 8 + r] * f;
  }
  #pragma unroll
  for (int off = 32; off > 0; off >>= 1) {
    a0 += __shfl_xor(a0, off, 64);
    a1 += __shfl_xor(a1, off, 64);
  }
  if (lane == 0) {
    out[t] = a0 + b2[0];
    out[TLEN + t] = a1 + b2[1];
  }
}

extern "C" void kernel_launch(void* const* d_in, const int* in_sizes, int n_in,
                              void* d_out, int out_size, void* d_ws, size_t ws_size,
                              hipStream_t stream) {
  (void)in_sizes; (void)n_in; (void)out_size; (void)ws_size;
  const float* x       = (const float*)d_in[0];
  const float* c       = (const float*)d_in[1];
  const float* front_w = (const float*)d_in[2];
  const float* front_b = (const float*)d_in[3];
  const float* filt_w  = (const float*)d_in[4];
  const float* filt_b  = (const float*)d_in[5];
  const float* gate_w  = (const float*)d_in[6];
  const float* gate_b  = (const float*)d_in[7];
  const float* cf_w    = (const float*)d_in[8];
  const float* cf_b    = (const float*)d_in[9];
  const float* cg_w    = (const float*)d_in[10];
  const float* cg_b    = (const float*)d_in[11];
  const float* res_w   = (const float*)d_in[12];
  const float* res_b   = (const float*)d_in[13];
  const float* skip_w  = (const float*)d_in[14];
  const float* skip_b  = (const float*)d_in[15];
  const float* fin1_w  = (const float*)d_in[16];
  const float* fin1_b  = (const float*)d_in[17];
  const float* fin2_w  = (const float*)d_in[18];
  const float* fin2_b  = (const float*)d_in[19];
  const float* up_w    = (const float*)d_in[20];
  const float* up_b    = (const float*)d_in[21];

  char* ws = (char*)d_ws;
  auto alloc = [&](size_t bytes) {
    char* p = ws;
    ws += (bytes + 255) & ~(size_t)255;
    return p;
  };
  unsigned short* WA     = (unsigned short*)alloc((size_t)30 * 2 * 1024 * 512 * 2);
  unsigned short* RS     = (unsigned short*)alloc((size_t)30 * 1024 * 512 * 2);
  unsigned short* CA     = (unsigned short*)alloc((size_t)30 * 1024 * 128 * 2);
  unsigned short* F1c    = (unsigned short*)alloc((size_t)512 * 512 * 2);
  float* fgb             = (float*)alloc((size_t)30 * 1024 * 4);
  float* u1              = (float*)alloc((size_t)128 * 256 * 4);
  unsigned short* cu     = (unsigned short*)alloc((size_t)TLEN * 128 * 2);
  float* hf              = (float*)alloc((size_t)TLEN * 512 * 4);
  unsigned short* hbf    = (unsigned short*)alloc((size_t)(HPADT + TLEN + 384) * 512 * 2);  // slack for union over-stage
  unsigned short* obf    = (unsigned short*)alloc((size_t)TLEN * 512 * 2);
  float* skip            = (float*)alloc((size_t)TLEN * 512 * 4);
  unsigned short* skipbf = (unsigned short*)alloc((size_t)TLEN * 512 * 2);
  unsigned short* t1     = (unsigned short*)alloc((size_t)TLEN * 512 * 2);
  float* out             = (float*)d_out;

  // zero the left pad of hbf (tap t-d reads 0 for t < d)
  hipMemsetAsync(hbf, 0, (size_t)HPADT * 512 * 2, stream);

  for (int g = 0; g < 6; ++g)
    cast_wa_kernel<<<512, 256, 0, stream>>>(filt_w, gate_w, WA, g * 327680, 327680);
  for (int g = 0; g < 6; ++g)
    cast_rs_kernel<<<512, 256, 0, stream>>>(res_w, skip_w, RS, g * 327680, 327680);
  cast_misc_kernel<<<512, 256, 0, stream>>>(cf_w, cg_w, fin1_w, filt_b, cf_b,
                                            gate_b, cg_b, CA, F1c, fgb);

  upsample1_kernel<<<dim3(128), 256, 0, stream>>>(c, up_w, up_b, u1);
  upsample2_kernel<<<dim3(16, 128), 256, 0, stream>>>(u1, up_w, up_b, cu);
  front_kernel<<<dim3(512, 2), 256, 0, stream>>>(x, front_w, front_b, hf, hbf);

  for (int l = 0; l < 30; ++l) {
    int d = 1 << (l % 10);
    if (d <= 64) {
      gemm_a_smalld_kernel<<<dim3(16, 16), 512, 0, stream>>>(
          WA + (size_t)l * 2 * 524288, CA + (size_t)l * 131072,
          fgb + (size_t)l * 1024, hbf, cu, obf, d);
    } else {
      gemm_a_bigd_kernel<<<dim3(16, 16), 512, 0, stream>>>(
          WA + (size_t)l * 2 * 524288, CA + (size_t)l * 131072,
          fgb + (size_t)l * 1024, hbf, cu, obf, d);
    }
    gemm_b_kernel<<<dim3(16, 16), 512, 0, stream>>>(
        RS + (size_t)l * 524288,
        res_b + (size_t)l * 512, skip_b + (size_t)l * 512,
        obf, hf, hbf, skip, skipbf, (l == 0) ? 1 : 0, (l == 29) ? 1 : 0);
  }

  final1_kernel<<<dim3(32, 8), 256, 0, stream>>>(F1c, fin1_b, skipbf, t1);
  final2_kernel<<<1024, 256, 0, stream>>>(fin2_w, fin2_b, t1, out);
}

// Round 7
// 1191.393 us; speedup vs baseline: 1.1625x; 1.1625x over previous
//
#include <hip/hip_runtime.h>
#include <hip/hip_bf16.h>

#define TLEN 4096
#define HPADT 512
#define SQRT_HALF 0.70710678118654752f

typedef __attribute__((ext_vector_type(8))) short short8;
typedef __attribute__((ext_vector_type(4))) float floatx4;
typedef __attribute__((ext_vector_type(4))) unsigned short ushort4v;

#define MFMA_BF16(a, b, c) __builtin_amdgcn_mfma_f32_16x16x32_bf16((a), (b), (c), 0, 0, 0)

__device__ __forceinline__ float bf2f(unsigned short u) {
  union { unsigned int i; float f; } v; v.i = ((unsigned int)u) << 16; return v.f;
}
__device__ __forceinline__ unsigned short f2bf(float x) {
  union { float f; unsigned int i; } v; v.f = x;
  unsigned int r = v.i + 0x7FFFu + ((v.i >> 16) & 1u);
  return (unsigned short)(r >> 16);
}
__device__ __forceinline__ short8 ld8(const unsigned short* p) { return *(const short8*)p; }

// ---- 128-elem-row staging (used by final1) ----
template <int NI>
__device__ __forceinline__ void stage128(unsigned short* lds, const unsigned short* src,
                                         int stride, int tid) {
  #pragma unroll
  for (int inst = 0; inst < NI; ++inst) {
    int qb = inst * 256 + (tid & 192);   // wave-uniform chunk base
    int q = qb + (tid & 63);
    int r = q >> 4;
    int c = (q & 15) ^ (r & 15);
    __builtin_amdgcn_global_load_lds(
        (const __attribute__((address_space(1))) unsigned int*)(src + (size_t)r * stride + (c << 3)),
        (__attribute__((address_space(3))) unsigned int*)(lds + qb * 8),
        16, 0, 0);
  }
}
__device__ __forceinline__ short8 frag128(const unsigned short* lds, int r, int cj) {
  return *(const short8*)(lds + r * 128 + ((cj ^ (r & 15)) << 3));
}

// ---- 64-elem-row staging (loop GEMMs, BK=64) ----
// Stages NI*32 rows of 64 bf16. Data chunk c of row r lands at slot (c ^ (r&7)).
template <int NI>
__device__ __forceinline__ void stage64(unsigned short* lds, const unsigned short* src,
                                        int stride, int tid) {
  #pragma unroll
  for (int inst = 0; inst < NI; ++inst) {
    int qb = inst * 256 + (tid & 192);   // wave-uniform chunk base
    int q = qb + (tid & 63);
    int r = q >> 3;                       // 8 chunks (of 8 shorts) per row
    int c = (q & 7) ^ (r & 7);
    __builtin_amdgcn_global_load_lds(
        (const __attribute__((address_space(1))) unsigned int*)(src + (size_t)r * stride + (c << 3)),
        (__attribute__((address_space(3))) unsigned int*)(lds + qb * 8),
        16, 0, 0);
  }
}
__device__ __forceinline__ short8 frag64(const unsigned short* lds, int r, int cj) {
  return *(const short8*)(lds + r * 64 + ((cj ^ (r & 7)) << 3));
}

// Counted waits (depth-3 pipeline)
__device__ __forceinline__ void wait_vm12() { asm volatile("s_waitcnt vmcnt(12)" ::: "memory"); }
__device__ __forceinline__ void wait_vm6()  { asm volatile("s_waitcnt vmcnt(6)"  ::: "memory"); }
__device__ __forceinline__ void wait_vm0()  { asm volatile("s_waitcnt vmcnt(0)"  ::: "memory"); }

// ============ weight pre-cast, split into small grid-strided dispatches ============
__global__ __launch_bounds__(256) void cast_wa_kernel(
    const float* __restrict__ fw, const float* __restrict__ gw,
    unsigned short* __restrict__ WA, int base, int count)
{
  for (int i = blockIdx.x * 256 + threadIdx.x; i < count; i += gridDim.x * 256) {
    size_t idx = (size_t)base + i;
    size_t l = idx >> 16;
    int o = (int)((idx >> 7) & 511);
    int i4 = (int)(idx & 127) * 4;
    const float4* fp = (const float4*)(fw + (((l * 512 + o) * 512 + i4) * 2));
    const float4* gp = (const float4*)(gw + (((l * 512 + o) * 512 + i4) * 2));
    float4 f0 = fp[0], f1v = fp[1];
    float4 g0 = gp[0], g1 = gp[1];
    size_t base0 = ((l * 2 + 0) * 1024);
    size_t base1 = ((l * 2 + 1) * 1024);
    *(ushort4v*)&WA[(base0 + o) * 512 + i4]       = (ushort4v){f2bf(f0.x), f2bf(f0.z), f2bf(f1v.x), f2bf(f1v.z)};
    *(ushort4v*)&WA[(base1 + o) * 512 + i4]       = (ushort4v){f2bf(f0.y), f2bf(f0.w), f2bf(f1v.y), f2bf(f1v.w)};
    *(ushort4v*)&WA[(base0 + 512 + o) * 512 + i4] = (ushort4v){f2bf(g0.x), f2bf(g0.z), f2bf(g1.x), f2bf(g1.z)};
    *(ushort4v*)&WA[(base1 + 512 + o) * 512 + i4] = (ushort4v){f2bf(g0.y), f2bf(g0.w), f2bf(g1.y), f2bf(g1.w)};
  }
}

__global__ __launch_bounds__(256) void cast_rs_kernel(
    const float* __restrict__ rw, const float* __restrict__ sw,
    unsigned short* __restrict__ RS, int base, int count)
{
  for (int i = blockIdx.x * 256 + threadIdx.x; i < count; i += gridDim.x * 256) {
    size_t idx = (size_t)base + i;
    size_t l = idx >> 16;
    int o = (int)((idx >> 7) & 511);
    int i4 = (int)(idx & 127) * 4;
    float4 r4 = *(const float4*)(rw + ((l * 512 + o) * 512 + i4));
    float4 s4 = *(const float4*)(sw + ((l * 512 + o) * 512 + i4));
    *(ushort4v*)&RS[(l * 1024 + o) * 512 + i4]       = (ushort4v){f2bf(r4.x), f2bf(r4.y), f2bf(r4.z), f2bf(r4.w)};
    *(ushort4v*)&RS[(l * 1024 + 512 + o) * 512 + i4] = (ushort4v){f2bf(s4.x), f2bf(s4.y), f2bf(s4.z), f2bf(s4.w)};
  }
}

__global__ __launch_bounds__(256) void cast_misc_kernel(
    const float* __restrict__ cf, const float* __restrict__ cg,
    const float* __restrict__ f1, const float* __restrict__ fb,
    const float* __restrict__ cfb, const float* __restrict__ gb,
    const float* __restrict__ cgb,
    unsigned short* __restrict__ CA, unsigned short* __restrict__ F1c,
    float* __restrict__ fgb)
{
  const int total = 491520 + 65536 + 30720;
  for (int i = blockIdx.x * 256 + threadIdx.x; i < total; i += gridDim.x * 256) {
    if (i < 491520) {
      size_t idx = i;
      size_t l = idx >> 14;
      int o = (int)((idx >> 5) & 511);
      int i4 = (int)(idx & 31) * 4;
      float4 f4 = *(const float4*)(cf + ((l * 512 + o) * 128 + i4));
      float4 g4 = *(const float4*)(cg + ((l * 512 + o) * 128 + i4));
      *(ushort4v*)&CA[(l * 1024 + o) * 128 + i4]       = (ushort4v){f2bf(f4.x), f2bf(f4.y), f2bf(f4.z), f2bf(f4.w)};
      *(ushort4v*)&CA[(l * 1024 + 512 + o) * 128 + i4] = (ushort4v){f2bf(g4.x), f2bf(g4.y), f2bf(g4.z), f2bf(g4.w)};
    } else if (i < 491520 + 65536) {
      size_t idx = i - 491520;
      float4 v = *(const float4*)(f1 + idx * 4);
      *(ushort4v*)&F1c[idx * 4] = (ushort4v){f2bf(v.x), f2bf(v.y), f2bf(v.z), f2bf(v.w)};
    } else {
      int idx = i - (491520 + 65536);
      int l = idx >> 10, r = idx & 1023;
      float v;
      if (r < 512) v = fb[l * 512 + r] + cfb[l * 512 + r];
      else         v = gb[l * 512 + r - 512] + cgb[l * 512 + r - 512];
      fgb[idx] = v;
    }
  }
}

// ============ upsample ============

__global__ __launch_bounds__(256) void upsample1_kernel(
    const float* __restrict__ c, const float* __restrict__ up_w,
    const float* __restrict__ up_b, float* __restrict__ u1)
{
  int x = threadIdx.x;
  int h = blockIdx.x;
  const float* w = up_w;
  float acc = 0.f;
  int k1 = (23 - x) & 15;
  #pragma unroll
  for (int dk = 0; dk < 2; ++dk) {
    int kx = k1 + 16 * dk;
    int num = x + kx - 23;
    if (num >= 0) {
      int qq = num >> 4;
      if (qq < 16) {
        #pragma unroll
        for (int ky = 0; ky < 3; ++ky) {
          int hh = h + ky - 1;
          if (hh >= 0 && hh < 128)
            acc += c[hh * 16 + qq] * w[(2 - ky) * 32 + (31 - kx)];
        }
      }
    }
  }
  acc += up_b[0];
  u1[h * 256 + x] = acc > 0.f ? acc : 0.4f * acc;
}

__global__ __launch_bounds__(256) void upsample2_kernel(
    const float* __restrict__ u1, const float* __restrict__ up_w,
    const float* __restrict__ up_b, unsigned short* __restrict__ cu)
{
  int x = blockIdx.x * 256 + threadIdx.x;
  int h = blockIdx.y;
  const float* w = up_w + 96;
  float acc = 0.f;
  int k1 = (23 - x) & 15;
  #pragma unroll
  for (int dk = 0; dk < 2; ++dk) {
    int kx = k1 + 16 * dk;
    int num = x + kx - 23;
    if (num >= 0) {
      int qq = num >> 4;
      if (qq < 256) {
        #pragma unroll
        for (int ky = 0; ky < 3; ++ky) {
          int hh = h + ky - 1;
          if (hh >= 0 && hh < 128)
            acc += u1[hh * 256 + qq] * w[(2 - ky) * 32 + (31 - kx)];
        }
      }
    }
  }
  acc += up_b[1];
  acc = acc > 0.f ? acc : 0.4f * acc;
  cu[(size_t)x * 128 + h] = f2bf(acc);
}

// ============ front conv -> hbf[t][512] (bf16 only; fp32 hf removed) ============
__global__ __launch_bounds__(256) void front_kernel(
    const float* __restrict__ x, const float* __restrict__ fw, const float* __restrict__ fb,
    unsigned short* __restrict__ hbf)
{
  __shared__ float xs[40];
  int tid = threadIdx.x;
  int o = blockIdx.y * 256 + tid;
  int t0 = blockIdx.x * 8;
  if (tid < 39) {
    int gx = t0 - 31 + tid;
    xs[tid] = (gx >= 0) ? x[gx] : 0.f;
  }
  __syncthreads();
  float w[32];
  #pragma unroll
  for (int k = 0; k < 32; ++k) w[k] = fw[o * 32 + k];
  float b = fb[o];
  #pragma unroll
  for (int j = 0; j < 8; ++j) {
    float acc = b;
    #pragma unroll
    for (int k = 0; k < 32; ++k) acc += w[k] * xs[j + k];
    acc = acc > 0.f ? acc : 0.f;
    int t = t0 + j;
    hbf[(size_t)(HPADT + t) * 512 + o] = f2bf(acc);
  }
}

// ============ gemm_a_smalld: d < 128, union X staging ============
// Taps t-d and t overlap: stage hbf rows [t0-d, t0+XU*32) ONCE per k-chunk;
// tap0 frag = row (t-t0), tap1 frag = row (t-t0+d). Plain dbuf-syncthreads.
template <int XU>
__global__ __launch_bounds__(256, 2) void gemm_a_smalld_kernel(
    const unsigned short* __restrict__ WA,   // [2][1024][512]
    const unsigned short* __restrict__ CA,   // [1024][128]
    const float* __restrict__ fgb,           // [1024]
    const unsigned short* __restrict__ hbf,  // [(HPADT+T+slack)][512]
    const unsigned short* __restrict__ cu,   // [T][128]
    unsigned short* __restrict__ obf,        // [T][512]
    const int d)
{
  __shared__ unsigned short U[2][XU * 32 * 64];
  __shared__ unsigned short Aw[2][4][32 * 64];   // F-tap0, F-tap1, G-tap0, G-tap1

  const int tid = threadIdx.x;
  const int lane = tid & 63;
  const int wave = tid >> 6;
  const int lm = lane & 15, qd = lane >> 4;
  const int n0 = blockIdx.x * 128;
  const int m0 = blockIdx.y * 32;
  const int wn = wave * 32;
  const int NS = 10;

  floatx4 accF[2][2], accG[2][2];
  #pragma unroll
  for (int a = 0; a < 2; ++a)
    #pragma unroll
    for (int b = 0; b < 2; ++b) {
      accF[a][b] = (floatx4){0.f, 0.f, 0.f, 0.f};
      accG[a][b] = (floatx4){0.f, 0.f, 0.f, 0.f};
    }

  auto stage_step = [&](int s, int b) {
    if (s < 8) {
      int k0 = s * 64;
      stage64<XU>(&U[b][0], hbf + (size_t)(HPADT + n0 - d) * 512 + k0, 512, tid);
      stage64<1>(&Aw[b][0][0], WA + (size_t)m0 * 512 + k0, 512, tid);
      stage64<1>(&Aw[b][1][0], WA + 524288 + (size_t)m0 * 512 + k0, 512, tid);
      stage64<1>(&Aw[b][2][0], WA + (size_t)(512 + m0) * 512 + k0, 512, tid);
      stage64<1>(&Aw[b][3][0], WA + 524288 + (size_t)(512 + m0) * 512 + k0, 512, tid);
    } else {
      int k0 = (s - 8) * 64;
      stage64<4>(&U[b][0], cu + (size_t)n0 * 128 + k0, 128, tid);
      stage64<1>(&Aw[b][0][0], CA + (size_t)m0 * 128 + k0, 128, tid);
      stage64<1>(&Aw[b][2][0], CA + (size_t)(512 + m0) * 128 + k0, 128, tid);
    }
  };

  stage_step(0, 0);
  #pragma unroll 1
  for (int s = 0; s < NS; ++s) {
    __syncthreads();
    if (s + 1 < NS) stage_step(s + 1, (s + 1) & 1);
    const unsigned short* u   = &U[s & 1][0];
    const unsigned short* af0 = &Aw[s & 1][0][0];
    const unsigned short* af1 = &Aw[s & 1][1][0];
    const unsigned short* ag0 = &Aw[s & 1][2][0];
    const unsigned short* ag1 = &Aw[s & 1][3][0];
    if (s < 8) {
      #pragma unroll
      for (int j = 0; j < 2; ++j) {
        int cj = j * 4 + qd;
        short8 f0a = frag64(af0, lm, cj),      f0b = frag64(af0, 16 + lm, cj);
        short8 f1a = frag64(af1, lm, cj),      f1b = frag64(af1, 16 + lm, cj);
        short8 g0a = frag64(ag0, lm, cj),      g0b = frag64(ag0, 16 + lm, cj);
        short8 g1a = frag64(ag1, lm, cj),      g1b = frag64(ag1, 16 + lm, cj);
        short8 x0 = frag64(u, wn + lm, cj);
        short8 x1 = frag64(u, wn + 16 + lm, cj);
        short8 y0 = frag64(u, d + wn + lm, cj);
        short8 y1 = frag64(u, d + wn + 16 + lm, cj);
        accF[0][0] = MFMA_BF16(f0a, x0, accF[0][0]);
        accF[0][0] = MFMA_BF16(f1a, y0, accF[0][0]);
        accF[0][1] = MFMA_BF16(f0a, x1, accF[0][1]);
        accF[0][1] = MFMA_BF16(f1a, y1, accF[0][1]);
        accF[1][0] = MFMA_BF16(f0b, x0, accF[1][0]);
        accF[1][0] = MFMA_BF16(f1b, y0, accF[1][0]);
        accF[1][1] = MFMA_BF16(f0b, x1, accF[1][1]);
        accF[1][1] = MFMA_BF16(f1b, y1, accF[1][1]);
        accG[0][0] = MFMA_BF16(g0a, x0, accG[0][0]);
        accG[0][0] = MFMA_BF16(g1a, y0, accG[0][0]);
        accG[0][1] = MFMA_BF16(g0a, x1, accG[0][1]);
        accG[0][1] = MFMA_BF16(g1a, y1, accG[0][1]);
        accG[1][0] = MFMA_BF16(g0b, x0, accG[1][0]);
        accG[1][0] = MFMA_BF16(g1b, y0, accG[1][0]);
        accG[1][1] = MFMA_BF16(g0b, x1, accG[1][1]);
        accG[1][1] = MFMA_BF16(g1b, y1, accG[1][1]);
      }
    } else {
      #pragma unroll
      for (int j = 0; j < 2; ++j) {
        int cj = j * 4 + qd;
        short8 fa = frag64(af0, lm, cj), fbv = frag64(af0, 16 + lm, cj);
        short8 ga = frag64(ag0, lm, cj), gbv = frag64(ag0, 16 + lm, cj);
        short8 x0 = frag64(u, wn + lm, cj);
        short8 x1 = frag64(u, wn + 16 + lm, cj);
        accF[0][0] = MFMA_BF16(fa, x0, accF[0][0]);
        accF[0][1] = MFMA_BF16(fa, x1, accF[0][1]);
        accF[1][0] = MFMA_BF16(fbv, x0, accF[1][0]);
        accF[1][1] = MFMA_BF16(fbv, x1, accF[1][1]);
        accG[0][0] = MFMA_BF16(ga, x0, accG[0][0]);
        accG[0][1] = MFMA_BF16(ga, x1, accG[0][1]);
        accG[1][0] = MFMA_BF16(gbv, x0, accG[1][0]);
        accG[1][1] = MFMA_BF16(gbv, x1, accG[1][1]);
      }
    }
  }

  #pragma unroll
  for (int mt = 0; mt < 2; ++mt) {
    int oc0 = m0 + mt * 16 + qd * 4;
    floatx4 fb4 = *(const floatx4*)&fgb[oc0];
    floatx4 gb4 = *(const floatx4*)&fgb[512 + oc0];
    #pragma unroll
    for (int nt = 0; nt < 2; ++nt) {
      int t = n0 + wn + nt * 16 + lm;
      ushort4v o4;
      #pragma unroll
      for (int r = 0; r < 4; ++r) {
        float f = accF[mt][nt][r] + fb4[r];
        float g = accG[mt][nt][r] + gb4[r];
        float ef = __expf(-2.f * f);
        float th = (1.f - ef) / (1.f + ef);
        float sg = 1.f / (1.f + __expf(-g));
        o4[r] = f2bf(th * sg);
      }
      *(ushort4v*)&obf[(size_t)t * 512 + oc0] = o4;
    }
  }
}

// ============ gemm_a: d >= 128, disjoint taps, depth-3 counted-vmcnt pipeline ============
__global__ __launch_bounds__(256, 2) void gemm_a_kernel(
    const unsigned short* __restrict__ WA,   // [2][1024][512]
    const unsigned short* __restrict__ CA,   // [1024][128]
    const float* __restrict__ fgb,           // [1024]
    const unsigned short* __restrict__ hbf,  // [(HPADT+T+slack)][512]
    const unsigned short* __restrict__ cu,   // [T][128]
    unsigned short* __restrict__ obf,        // [T][512]
    const int d)
{
  __shared__ unsigned short Af[3][32 * 64];
  __shared__ unsigned short Ag[3][32 * 64];
  __shared__ unsigned short Xs[3][128 * 64];

  const int tid = threadIdx.x;
  const int lane = tid & 63;
  const int wave = tid >> 6;
  const int lm = lane & 15, qd = lane >> 4;
  const int n0 = blockIdx.x * 128;
  const int m0 = blockIdx.y * 32;
  const int wn = wave * 32;
  const int NS = 18;

  floatx4 accF[2][2], accG[2][2];
  #pragma unroll
  for (int a = 0; a < 2; ++a)
    #pragma unroll
    for (int b = 0; b < 2; ++b) {
      accF[a][b] = (floatx4){0.f, 0.f, 0.f, 0.f};
      accG[a][b] = (floatx4){0.f, 0.f, 0.f, 0.f};
    }

  auto stage_step = [&](int s, int b) {   // 6 VMEM instructions per wave
    if (s < 16) {
      int tap = s >> 3;
      int k0 = (s & 7) * 64;
      const unsigned short* ab = WA + (size_t)tap * 524288;
      stage64<1>(&Af[b][0], ab + (size_t)m0 * 512 + k0, 512, tid);
      stage64<1>(&Ag[b][0], ab + (size_t)(512 + m0) * 512 + k0, 512, tid);
      stage64<4>(&Xs[b][0], hbf + (size_t)(HPADT + n0 - (tap ? 0 : d)) * 512 + k0, 512, tid);
    } else {
      int k0 = (s - 16) * 64;
      stage64<1>(&Af[b][0], CA + (size_t)m0 * 128 + k0, 128, tid);
      stage64<1>(&Ag[b][0], CA + (size_t)(512 + m0) * 128 + k0, 128, tid);
      stage64<4>(&Xs[b][0], cu + (size_t)n0 * 128 + k0, 128, tid);
    }
  };

  stage_step(0, 0);
  stage_step(1, 1);
  int cur = 0;
  #pragma unroll 1
  for (int s = 0; s < NS; ++s) {
    int stg = cur + 2; if (stg >= 3) stg -= 3;
    if (s + 2 < NS) stage_step(s + 2, stg);
    if (s + 2 < NS)      wait_vm12();
    else if (s + 1 < NS) wait_vm6();
    else                 wait_vm0();
    __builtin_amdgcn_s_barrier();
    __builtin_amdgcn_sched_barrier(0);
    const unsigned short* af = &Af[cur][0];
    const unsigned short* ag = &Ag[cur][0];
    const unsigned short* xs = &Xs[cur][0];
    __builtin_amdgcn_s_setprio(1);
    #pragma unroll
    for (int j = 0; j < 2; ++j) {
      int cj = j * 4 + qd;
      short8 a0 = frag64(af, lm, cj);
      short8 a1 = frag64(af, 16 + lm, cj);
      short8 g0 = frag64(ag, lm, cj);
      short8 g1 = frag64(ag, 16 + lm, cj);
      short8 x0 = frag64(xs, wn + lm, cj);
      short8 x1 = frag64(xs, wn + 16 + lm, cj);
      accF[0][0] = MFMA_BF16(a0, x0, accF[0][0]);
      accF[0][1] = MFMA_BF16(a0, x1, accF[0][1]);
      accF[1][0] = MFMA_BF16(a1, x0, accF[1][0]);
      accF[1][1] = MFMA_BF16(a1, x1, accF[1][1]);
      accG[0][0] = MFMA_BF16(g0, x0, accG[0][0]);
      accG[0][1] = MFMA_BF16(g0, x1, accG[0][1]);
      accG[1][0] = MFMA_BF16(g1, x0, accG[1][0]);
      accG[1][1] = MFMA_BF16(g1, x1, accG[1][1]);
    }
    __builtin_amdgcn_s_setprio(0);
    __builtin_amdgcn_sched_barrier(0);
    __builtin_amdgcn_s_barrier();
    __builtin_amdgcn_sched_barrier(0);
    cur = (cur == 2) ? 0 : cur + 1;
  }

  #pragma unroll
  for (int mt = 0; mt < 2; ++mt) {
    int oc0 = m0 + mt * 16 + qd * 4;
    floatx4 fb4 = *(const floatx4*)&fgb[oc0];
    floatx4 gb4 = *(const floatx4*)&fgb[512 + oc0];
    #pragma unroll
    for (int nt = 0; nt < 2; ++nt) {
      int t = n0 + wn + nt * 16 + lm;
      ushort4v o4;
      #pragma unroll
      for (int r = 0; r < 4; ++r) {
        float f = accF[mt][nt][r] + fb4[r];
        float g = accG[mt][nt][r] + gb4[r];
        float ef = __expf(-2.f * f);
        float th = (1.f - ef) / (1.f + ef);
        float sg = 1.f / (1.f + __expf(-g));
        o4[r] = f2bf(th * sg);
      }
      *(ushort4v*)&obf[(size_t)t * 512 + oc0] = o4;
    }
  }
}

// ============ gemm_b: dual R/S, 32oc x 128t, BK=64, depth-3 counted-vmcnt ============
// h carry now lives in hbf (bf16) only: epilogue reads hbf, adds R, rescales,
// writes hbf. fp32 hf buffer eliminated (-12 MB/layer traffic).
__global__ __launch_bounds__(256, 2) void gemm_b_kernel(
    const unsigned short* __restrict__ RS,   // [1024][512]
    const float* __restrict__ rb, const float* __restrict__ sb,
    const unsigned short* __restrict__ obf,  // [T][512]
    unsigned short* __restrict__ hbf,
    float* __restrict__ skip, unsigned short* __restrict__ skipbf,
    const int first, const int last)
{
  __shared__ unsigned short Ar[3][32 * 64];
  __shared__ unsigned short As_[3][32 * 64];
  __shared__ unsigned short Xs[3][128 * 64];

  const int tid = threadIdx.x;
  const int lane = tid & 63;
  const int wave = tid >> 6;
  const int lm = lane & 15, qd = lane >> 4;
  const int n0 = blockIdx.x * 128;
  const int m0 = blockIdx.y * 32;
  const int wn = wave * 32;
  const int NS = 8;

  floatx4 accR[2][2], accS[2][2];
  #pragma unroll
  for (int a = 0; a < 2; ++a)
    #pragma unroll
    for (int b = 0; b < 2; ++b) {
      accR[a][b] = (floatx4){0.f, 0.f, 0.f, 0.f};
      accS[a][b] = (floatx4){0.f, 0.f, 0.f, 0.f};
    }

  auto stage_step = [&](int s, int b) {   // 6 VMEM instructions per wave
    int k0 = s * 64;
    stage64<1>(&Ar[b][0], RS + (size_t)m0 * 512 + k0, 512, tid);
    stage64<1>(&As_[b][0], RS + (size_t)(512 + m0) * 512 + k0, 512, tid);
    stage64<4>(&Xs[b][0], obf + (size_t)n0 * 512 + k0, 512, tid);
  };

  stage_step(0, 0);
  stage_step(1, 1);
  int cur = 0;
  #pragma unroll 1
  for (int s = 0; s < NS; ++s) {
    int stg = cur + 2; if (stg >= 3) stg -= 3;
    if (s + 2 < NS) stage_step(s + 2, stg);
    if (s + 2 < NS)      wait_vm12();
    else if (s + 1 < NS) wait_vm6();
    else                 wait_vm0();
    __builtin_amdgcn_s_barrier();
    __builtin_amdgcn_sched_barrier(0);
    const unsigned short* ar = &Ar[cur][0];
    const unsigned short* as = &As_[cur][0];
    const unsigned short* xs = &Xs[cur][0];
    __builtin_amdgcn_s_setprio(1);
    #pragma unroll
    for (int j = 0; j < 2; ++j) {
      int cj = j * 4 + qd;
      short8 a0 = frag64(ar, lm, cj);
      short8 a1 = frag64(ar, 16 + lm, cj);
      short8 g0 = frag64(as, lm, cj);
      short8 g1 = frag64(as, 16 + lm, cj);
      short8 x0 = frag64(xs, wn + lm, cj);
      short8 x1 = frag64(xs, wn + 16 + lm, cj);
      accR[0][0] = MFMA_BF16(a0, x0, accR[0][0]);
      accR[0][1] = MFMA_BF16(a0, x1, accR[0][1]);
      accR[1][0] = MFMA_BF16(a1, x0, accR[1][0]);
      accR[1][1] = MFMA_BF16(a1, x1, accR[1][1]);
      accS[0][0] = MFMA_BF16(g0, x0, accS[0][0]);
      accS[0][1] = MFMA_BF16(g0, x1, accS[0][1]);
      accS[1][0] = MFMA_BF16(g1, x0, accS[1][0]);
      accS[1][1] = MFMA_BF16(g1, x1, accS[1][1]);
    }
    __builtin_amdgcn_s_setprio(0);
    __builtin_amdgcn_sched_barrier(0);
    __builtin_amdgcn_s_barrier();
    __builtin_amdgcn_sched_barrier(0);
    cur = (cur == 2) ? 0 : cur + 1;
  }

  #pragma unroll
  for (int mt = 0; mt < 2; ++mt) {
    int oc0 = m0 + mt * 16 + qd * 4;
    floatx4 rb4 = *(const floatx4*)&rb[oc0];
    floatx4 sb4 = *(const floatx4*)&sb[oc0];
    #pragma unroll
    for (int nt = 0; nt < 2; ++nt) {
      int t = n0 + wn + nt * 16 + lm;
      size_t base = (size_t)t * 512 + oc0;
      size_t hb = (size_t)(HPADT + t) * 512 + oc0;
      ushort4v hprev = *(const ushort4v*)&hbf[hb];
      floatx4 s4;
      if (first) s4 = (floatx4){0.f, 0.f, 0.f, 0.f};
      else s4 = *(const floatx4*)&skip[base];
      ushort4v hb4;
      #pragma unroll
      for (int r = 0; r < 4; ++r) {
        float hv = (bf2f(hprev[r]) + accR[mt][nt][r] + rb4[r]) * SQRT_HALF;
        hb4[r] = f2bf(hv);
        s4[r] = s4[r] + accS[mt][nt][r] + sb4[r];
      }
      *(ushort4v*)&hbf[hb] = hb4;
      *(floatx4*)&skip[base] = s4;
      if (last) {
        ushort4v sk4;
        #pragma unroll
        for (int r = 0; r < 4; ++r) sk4[r] = f2bf(s4[r] > 0.f ? s4[r] : 0.f);
        *(ushort4v*)&skipbf[base] = sk4;
      }
    }
  }
}

// ============ final1: tile 64 x 128, BK=128, dbuf LDS (96 KB) ============
__global__ __launch_bounds__(256) void final1_kernel(
    const unsigned short* __restrict__ W1,       // [512][512]
    const float* __restrict__ b1,
    const unsigned short* __restrict__ skipbf,   // [T][512]
    unsigned short* __restrict__ t1)
{
  __shared__ unsigned short Aw[2][64 * 128];
  __shared__ unsigned short Xs[2][128 * 128];

  const int tid = threadIdx.x;
  const int lane = tid & 63;
  const int wave = tid >> 6;
  const int lm = lane & 15, qd = lane >> 4;
  const int n0 = blockIdx.x * 128;
  const int m0 = blockIdx.y * 64;
  const int wm = (wave & 1) * 32;
  const int wn = (wave >> 1) * 64;

  floatx4 acc[2][4];
  #pragma unroll
  for (int a = 0; a < 2; ++a)
    #pragma unroll
    for (int b = 0; b < 4; ++b) acc[a][b] = (floatx4){0.f, 0.f, 0.f, 0.f};

  auto stage_step = [&](int s, int b) {
    int k0 = s * 128;
    stage128<4>(&Aw[b][0], W1 + (size_t)m0 * 512 + k0, 512, tid);
    stage128<8>(&Xs[b][0], skipbf + (size_t)n0 * 512 + k0, 512, tid);
  };

  stage_step(0, 0);
  for (int s = 0; s < 4; ++s) {
    __syncthreads();
    if (s < 3) stage_step(s + 1, (s + 1) & 1);
    const unsigned short* aw = &Aw[s & 1][0];
    const unsigned short* xs = &Xs[s & 1][0];
    #pragma unroll
    for (int j = 0; j < 4; ++j) {
      int cj = j * 4 + qd;
      short8 a[2], xv[4];
      a[0] = frag128(aw, wm + lm, cj);
      a[1] = frag128(aw, wm + 16 + lm, cj);
      #pragma unroll
      for (int nt = 0; nt < 4; ++nt) xv[nt] = frag128(xs, wn + nt * 16 + lm, cj);
      #pragma unroll
      for (int mt = 0; mt < 2; ++mt)
        #pragma unroll
        for (int nt = 0; nt < 4; ++nt)
          acc[mt][nt] = MFMA_BF16(a[mt], xv[nt], acc[mt][nt]);
    }
  }

  #pragma unroll
  for (int mt = 0; mt < 2; ++mt) {
    int oc0 = m0 + wm + mt * 16 + qd * 4;
    floatx4 b4 = *(const floatx4*)&b1[oc0];
    #pragma unroll
    for (int nt = 0; nt < 4; ++nt) {
      int t = n0 + wn + nt * 16 + lm;
      ushort4v o4;
      #pragma unroll
      for (int r = 0; r < 4; ++r) {
        float v = acc[mt][nt][r] + b4[r];
        o4[r] = f2bf(v > 0.f ? v : 0.f);
      }
      *(ushort4v*)&t1[(size_t)t * 512 + oc0] = o4;
    }
  }
}

// ============ final2: one wave per t, coalesced + shuffle reduce ============
__global__ __launch_bounds__(256) void final2_kernel(
    const float* __restrict__ W2, const float* __restrict__ b2,
    const unsigned short* __restrict__ t1, float* __restrict__ out)
{
  int wave = threadIdx.x >> 6, lane = threadIdx.x & 63;
  int t = blockIdx.x * 4 + wave;
  short8 v = ld8(t1 + (size_t)t * 512 + lane * 8);
  float a0 = 0.f, a1 = 0.f;
  #pragma unroll
  for (int r = 0; r < 8; ++r) {
    float f = bf2f((unsigned short)v[r]);
    a0 += W2[lane * 8 + r] * f;
    a1 += W2[512 + lane * 8 + r] * f;
  }
  #pragma unroll
  for (int off = 32; off > 0; off >>= 1) {
    a0 += __shfl_xor(a0, off, 64);
    a1 += __shfl_xor(a1, off, 64);
  }
  if (lane == 0) {
    out[t] = a0 + b2[0];
    out[TLEN + t] = a1 + b2[1];
  }
}

extern "C" void kernel_launch(void* const* d_in, const int* in_sizes, int n_in,
                              void* d_out, int out_size, void* d_ws, size_t ws_size,
                              hipStream_t stream) {
  (void)in_sizes; (void)n_in; (void)out_size; (void)ws_size;
  const float* x       = (const float*)d_in[0];
  const float* c       = (const float*)d_in[1];
  const float* front_w = (const float*)d_in[2];
  const float* front_b = (const float*)d_in[3];
  const float* filt_w  = (const float*)d_in[4];
  const float* filt_b  = (const float*)d_in[5];
  const float* gate_w  = (const float*)d_in[6];
  const float* gate_b  = (const float*)d_in[7];
  const float* cf_w    = (const float*)d_in[8];
  const float* cf_b    = (const float*)d_in[9];
  const float* cg_w    = (const float*)d_in[10];
  const float* cg_b    = (const float*)d_in[11];
  const float* res_w   = (const float*)d_in[12];
  const float* res_b   = (const float*)d_in[13];
  const float* skip_w  = (const float*)d_in[14];
  const float* skip_b  = (const float*)d_in[15];
  const float* fin1_w  = (const float*)d_in[16];
  const float* fin1_b  = (const float*)d_in[17];
  const float* fin2_w  = (const float*)d_in[18];
  const float* fin2_b  = (const float*)d_in[19];
  const float* up_w    = (const float*)d_in[20];
  const float* up_b    = (const float*)d_in[21];

  char* ws = (char*)d_ws;
  auto alloc = [&](size_t bytes) {
    char* p = ws;
    ws += (bytes + 255) & ~(size_t)255;
    return p;
  };
  unsigned short* WA     = (unsigned short*)alloc((size_t)30 * 2 * 1024 * 512 * 2);
  unsigned short* RS     = (unsigned short*)alloc((size_t)30 * 1024 * 512 * 2);
  unsigned short* CA     = (unsigned short*)alloc((size_t)30 * 1024 * 128 * 2);
  unsigned short* F1c    = (unsigned short*)alloc((size_t)512 * 512 * 2);
  float* fgb             = (float*)alloc((size_t)30 * 1024 * 4);
  float* u1              = (float*)alloc((size_t)128 * 256 * 4);
  unsigned short* cu     = (unsigned short*)alloc((size_t)TLEN * 128 * 2);
  unsigned short* hbf    = (unsigned short*)alloc((size_t)(HPADT + TLEN + 256) * 512 * 2);  // +slack for union over-stage
  unsigned short* obf    = (unsigned short*)alloc((size_t)TLEN * 512 * 2);
  float* skip            = (float*)alloc((size_t)TLEN * 512 * 4);
  unsigned short* skipbf = (unsigned short*)alloc((size_t)TLEN * 512 * 2);
  unsigned short* t1     = (unsigned short*)alloc((size_t)TLEN * 512 * 2);
  float* out             = (float*)d_out;

  // zero the left pad of hbf (tap t-d reads 0 for t < d)
  hipMemsetAsync(hbf, 0, (size_t)HPADT * 512 * 2, stream);

  // weight pre-cast: 13 small grid-strided dispatches
  for (int g = 0; g < 6; ++g)
    cast_wa_kernel<<<512, 256, 0, stream>>>(filt_w, gate_w, WA, g * 327680, 327680);
  for (int g = 0; g < 6; ++g)
    cast_rs_kernel<<<512, 256, 0, stream>>>(res_w, skip_w, RS, g * 327680, 327680);
  cast_misc_kernel<<<512, 256, 0, stream>>>(cf_w, cg_w, fin1_w, filt_b, cf_b,
                                            gate_b, cg_b, CA, F1c, fgb);

  upsample1_kernel<<<dim3(128), 256, 0, stream>>>(c, up_w, up_b, u1);
  upsample2_kernel<<<dim3(16, 128), 256, 0, stream>>>(u1, up_w, up_b, cu);
  front_kernel<<<dim3(512, 2), 256, 0, stream>>>(x, front_w, front_b, hbf);

  for (int l = 0; l < 30; ++l) {
    int d = 1 << (l % 10);
    if (d <= 32) {
      gemm_a_smalld_kernel<5><<<dim3(32, 16), 256, 0, stream>>>(
          WA + (size_t)l * 2 * 524288, CA + (size_t)l * 131072,
          fgb + (size_t)l * 1024, hbf, cu, obf, d);
    } else if (d == 64) {
      gemm_a_smalld_kernel<6><<<dim3(32, 16), 256, 0, stream>>>(
          WA + (size_t)l * 2 * 524288, CA + (size_t)l * 131072,
          fgb + (size_t)l * 1024, hbf, cu, obf, d);
    } else {
      gemm_a_kernel<<<dim3(32, 16), 256, 0, stream>>>(
          WA + (size_t)l * 2 * 524288, CA + (size_t)l * 131072,
          fgb + (size_t)l * 1024, hbf, cu, obf, d);
    }
    gemm_b_kernel<<<dim3(32, 16), 256, 0, stream>>>(
        RS + (size_t)l * 524288,
        res_b + (size_t)l * 512, skip_b + (size_t)l * 512,
        obf, hbf, skip, skipbf, (l == 0) ? 1 : 0, (l == 29) ? 1 : 0);
  }

  final1_kernel<<<dim3(32, 8), 256, 0, stream>>>(F1c, fin1_b, skipbf, t1);
  final2_kernel<<<1024, 256, 0, stream>>>(fin2_w, fin2_b, t1, out);
}